// Round 11
// baseline (231.459 us; speedup 1.0000x reference)
//
#include <hip/hip_runtime.h>
#include <stdint.h>

typedef unsigned short u16;
typedef __attribute__((ext_vector_type(4))) unsigned short u16x4;
typedef __attribute__((ext_vector_type(8))) short s16x8;   // 8 bf16 (MFMA A/B frag)
typedef __attribute__((ext_vector_type(2))) float f32x2;
typedef __attribute__((ext_vector_type(4))) float f32x4;   // MFMA C/D frag
typedef __attribute__((ext_vector_type(4), aligned(4))) float f32x4u;  // loads only

#define NROWS 100000
#define RPB   16
#define NBLK  (NROWS / RPB)   // 6250 exact
#define NTHR  512

// LDS pitches (elements)
#define PF   488   // fin  (bf16)
#define PS   360   // scb  (bf16) [scalar_in 128 | inv 224]
#define PH   136   // hb   (bf16)
#define PD   232   // dotb (bf16)
#define PA2  260   // aout (bf16) mlp_out cols 224..479 only (a_sv|a_ss)
#define PIF  132   // inner(f32)

// LDS arena (bytes). Overlay A: fin(S1->S2) ⊇ aout2(S5->S6).
//                    Overlay B: scb(S1->S4) ⊇ innerF(S5->S6).
#define OFF_FIN   0        // 16*488*2 = 15616
#define OFF_AOUT  0        // 16*260*2 =  8320  (⊂ fin)
#define OFF_SCB   15616    // 16*360*2 = 11520
#define OFF_INNER 15616    // 16*132*4 =  8448  (⊂ scb)
#define OFF_DOTB  27136    // 16*232*2 =  7424  (S2->S5)
#define OFF_HB    34560    // 16*136*2 =  4352  (S4->S5)
#define OFF_BCOM  38912    // 864*2    =  1728
#define ARENA_SZ  40640    // <= 40960 -> 4 blocks/CU (LDS-limited)

// packed-weight bases (elements) in d_ws (bf16 after pack)
#define B_UW0 0
#define B_UW1 16384
#define B_UW2 20480
#define B_VW0 21504
#define B_VW1 37888
#define B_VW2 41984
#define B_DW  43008
#define B_W1  71680
#define B_W2  116736
#define PACK_TOT 178176

__device__ inline float bf2f(u16 u) {
    union { uint32_t i; float f; } v; v.i = (uint32_t)u << 16; return v.f;
}
__device__ inline u16 f2bf(float f) {   // 1-op RNE via packed convert
    uint32_t d; asm("v_cvt_pk_bf16_f32 %0, %1, %1" : "=v"(d) : "v"(f)); return (u16)d;
}
__device__ inline uint32_t cvtpk(float lo, float hi) {
    uint32_t d; asm("v_cvt_pk_bf16_f32 %0, %1, %2" : "=v"(d) : "v"(lo), "v"(hi)); return d;
}
__device__ inline float wsum32(float v) {
    #pragma unroll
    for (int m = 16; m >= 1; m >>= 1) v += __shfl_xor(v, m);
    return v;
}

struct Ptrs {
    const float *xs, *xp, *lng, *lnb, *o3w, *o3b;
    const float *Uw0, *Uw1, *Uw2, *Ub0, *Vw0, *Vw1, *Vw2, *Vb0;
    const float *dw, *w1, *b1, *w2, *b2;
    const u16 *ws;
    float *out;
};

// Streamed-B tile accumulate (R5-proven low-VGPR form): B loaded inside the K loop.
template<int KS, bool PACKED>
__device__ inline f32x4 mm_acc(const u16* A, int pitchA, const void* W, int D,
                               int tile, int lane)
{
    f32x4 acc = {0.f, 0.f, 0.f, 0.f};
    const int r = lane & 15, g = lane >> 4;
    const u16* arow = A + r * pitchA + g * 8;
    #pragma unroll
    for (int ks = 0; ks < KS; ++ks) {
        s16x8 a = *(const s16x8*)(arow + ks * 32);
        s16x8 b;
        if (PACKED) {
            b = *(const s16x8*)((const u16*)W + (((size_t)tile * KS + ks) * 64 + (size_t)lane) * 8);
        } else {
            union { u16 u[8]; s16x8 v; } bb;
            const int k0 = ks * 32 + g * 8, o = tile * 16 + r;
            #pragma unroll
            for (int j = 0; j < 8; ++j)
                bb.u[j] = f2bf(((const float*)W)[(size_t)(k0 + j) * D + o]);
            b = bb.v;
        }
        acc = __builtin_amdgcn_mfma_f32_16x16x32_bf16(a, b, acc, 0, 0, 0);
    }
    return acc;
}

__global__ void pack_weights(Ptrs P, u16* ws)
{
    const int gid = blockIdx.x * 256 + threadIdx.x;
    if (gid >= PACK_TOT) return;
    const int  base[10] = {B_UW0, B_UW1, B_UW2, B_VW0, B_VW1, B_VW2, B_DW, B_W1, B_W2, PACK_TOT};
    const int  Kd[9]    = {128, 64, 32, 128, 64, 32, 224, 352, 128};
    const float* srcs[9] = {P.Uw0, P.Uw1, P.Uw2, P.Vw0, P.Vw1, P.Vw2, P.dw, P.w1, P.w2};
    const int  Dstride[9] = {128, 64, 32, 128, 64, 32, 128, 128, 480};
    int m = 0;
    for (int i = 1; i < 9; ++i) if (gid >= base[i]) m = i;
    const int e = gid - base[m];
    const int j = e & 7, lane = (e >> 3) & 63, tk = e >> 9;
    const int Ks = Kd[m] >> 5;
    const int ks = tk % Ks, tile = tk / Ks;
    const int k = ks * 32 + ((lane >> 4) << 3) + j;
    const int o = tile * 16 + (lane & 15);
    ws[gid] = f2bf(srcs[m][(size_t)k * Dstride[m] + o]);
}

// ---------------- stage 1: scalar LN + O3 layernorm (one row per half-wave) ----------------
__device__ inline void stage1_core(const Ptrs& P, u16* fin, u16* scb, int tid, int row0)
{
    const int rr = tid >> 5, l32 = tid & 31;
    const size_t row = (size_t)(row0 + rr);
    const float* xsf = P.xs + row * 128;
    const float* xpf = P.xp + row * 480;
    u16* finr = fin + rr * PF;
    u16* scbr = scb + rr * PS;
    {   // scalar layernorm -> scbr[0..127]
        f32x4 u = *(const f32x4*)(xsf + l32 * 4);
        float s  = u[0] + u[1] + u[2] + u[3];
        float s2 = u[0]*u[0] + u[1]*u[1] + u[2]*u[2] + u[3]*u[3];
        s = wsum32(s); s2 = wsum32(s2);
        const float mu = s * (1.f / 128.f);
        const float rs = 1.f / sqrtf(s2 * (1.f / 128.f) - mu * mu + 1e-5f);
        const int c = l32 * 4;
        float t[4];
        #pragma unroll
        for (int j2 = 0; j2 < 4; ++j2)
            t[j2] = (u[j2] - mu) * rs * P.lng[c + j2] + P.lnb[c + j2];
        *(uint32_t*)(scbr + c)     = cvtpk(t[0], t[1]);
        *(uint32_t*)(scbr + c + 2) = cvtpk(t[2], t[3]);
    }
    {   // s0 O3-LN -> finr[0..127]
        f32x4 u = *(const f32x4*)(xpf + l32 * 4);
        float s  = u[0] + u[1] + u[2] + u[3];
        float s2 = u[0]*u[0] + u[1]*u[1] + u[2]*u[2] + u[3]*u[3];
        s = wsum32(s); s2 = wsum32(s2);
        const float mu = s * (1.f / 128.f);
        const float rs = 1.f / sqrtf(s2 * (1.f / 128.f) - mu * mu + 1e-5f);
        const int c = l32 * 4;
        float t[4];
        #pragma unroll
        for (int j2 = 0; j2 < 4; ++j2)
            t[j2] = (u[j2] - mu) * rs * P.o3w[c + j2] + P.o3b[c + j2];
        *(uint32_t*)(finr + c)     = cvtpk(t[0], t[1]);
        *(uint32_t*)(finr + c + 2) = cvtpk(t[2], t[3]);
    }
    {   // s1 (64 irreps x 3) -> finr[128 + k*64 + i]
        const int cb = l32 * 6;
        f32x4u a = *(const f32x4u*)(xpf + 128 + cb);
        f32x2  b = *(const f32x2*)(xpf + 128 + cb + 4);
        float w[6] = {a[0], a[1], a[2], a[3], b[0], b[1]};
        float ss = 0.f;
        #pragma unroll
        for (int j2 = 0; j2 < 6; ++j2) ss += w[j2] * w[j2];
        ss = wsum32(ss);
        const float rs = 1.f / sqrtf(ss * (1.f / 192.f) + 1e-5f);
        #pragma unroll
        for (int j2 = 0; j2 < 6; ++j2) {
            const int c = cb + j2, i = c / 3, k = c - 3 * i;
            finr[128 + k * 64 + i] = f2bf(w[j2] * rs * P.o3w[128 + i]);
        }
    }
    {   // s2 (32 irreps x 5) -> finr[320 + k*32 + i]
        const int cb = l32 * 5;
        f32x4u a = *(const f32x4u*)(xpf + 320 + cb);
        float w[5] = {a[0], a[1], a[2], a[3], xpf[320 + cb + 4]};
        float ss = 0.f;
        #pragma unroll
        for (int j2 = 0; j2 < 5; ++j2) ss += w[j2] * w[j2];
        ss = wsum32(ss);
        const float rs = 1.f / sqrtf(ss * (1.f / 160.f) + 1e-5f);
        #pragma unroll
        for (int j2 = 0; j2 < 5; ++j2) {
            const int c = cb + j2, i = c / 5, k = c - 5 * i;
            finr[320 + k * 32 + i] = f2bf(w[j2] * rs * P.o3w[192 + i]);
        }
    }
}

template<bool PACKED>
__global__ __launch_bounds__(NTHR, 6) void xpainn_main(Ptrs P)
{
    __shared__ __align__(16) unsigned char arena[ARENA_SZ];
    u16*   fin    = (u16*)(arena + OFF_FIN);
    u16*   aout2  = (u16*)(arena + OFF_AOUT);    // mlp_out cols 224..479
    u16*   scb    = (u16*)(arena + OFF_SCB);
    float* innerF = (float*)(arena + OFF_INNER); // inner f32, overlays dead scb
    u16*   dotb   = (u16*)(arena + OFF_DOTB);
    u16*   hb     = (u16*)(arena + OFF_HB);
    u16*   bcom   = (u16*)(arena + OFF_BCOM);    // bf16 [Ub0 | Vb0 | b1 | b2(480)]

    const int tid = threadIdx.x;
    const int lane = tid & 63, wave = tid >> 6;
    const int r = lane & 15, g = lane >> 4;
    const int row0 = blockIdx.x * RPB;

    // biases -> LDS bf16
    for (int i = tid; i < 864; i += NTHR) {
        const float* src; int off;
        if (i < 128)      { src = P.Ub0; off = i; }
        else if (i < 256) { src = P.Vb0; off = i - 128; }
        else if (i < 384) { src = P.b1;  off = i - 256; }
        else              { src = P.b2;  off = i - 384; }
        bcom[i] = f2bf(src[off]);
    }
    stage1_core(P, fin, scb, tid, row0);
    __syncthreads();

    // ---------------- S2: U,V O3-linears, in-register inv/dot, U persists to S5 ----------------
    float u0r[4];          // l0 U, this wave's tile
    float uxr[5][4];       // l1 (3 used) / l2 (5 used) U channels
    {
        const int o = wave * 16 + r;
        f32x4 au = mm_acc<4, PACKED>(fin, PF,
            PACKED ? (const void*)(P.ws + B_UW0) : (const void*)P.Uw0, 128, wave, lane);
        f32x4 av = mm_acc<4, PACKED>(fin, PF,
            PACKED ? (const void*)(P.ws + B_VW0) : (const void*)P.Vw0, 128, wave, lane);
        const float bu = bf2f(bcom[o]), bv = bf2f(bcom[128 + o]);
        #pragma unroll
        for (int q = 0; q < 4; ++q) {
            const float U = au[q] * 0.08838834764831845f + bu;
            const float V = av[q] * 0.08838834764831845f + bv;
            u0r[q] = U;
            const int lrow = g * 4 + q;
            scb[lrow * PS + 128 + o] = f2bf(fabsf(V));
            dotb[lrow * PD + o]      = f2bf(U * V);
        }
    }
    if (wave < 4) {                 // l1: tile tt = wave, 3 channels, K=64
        const int tt = wave, o = tt * 16 + r;
        float sv[4] = {0.f,0.f,0.f,0.f}, suv[4] = {0.f,0.f,0.f,0.f};
        #pragma unroll
        for (int ch = 0; ch < 3; ++ch) {
            f32x4 au = mm_acc<2, PACKED>(fin + 128 + 64 * ch, PF,
                PACKED ? (const void*)(P.ws + B_UW1) : (const void*)P.Uw1, 64, tt, lane);
            f32x4 av = mm_acc<2, PACKED>(fin + 128 + 64 * ch, PF,
                PACKED ? (const void*)(P.ws + B_VW1) : (const void*)P.Vw1, 64, tt, lane);
            #pragma unroll
            for (int q = 0; q < 4; ++q) {
                const float U = au[q] * 0.125f, V = av[q] * 0.125f;
                uxr[ch][q] = U; sv[q] += V * V; suv[q] += U * V;
            }
        }
        #pragma unroll
        for (int q = 0; q < 4; ++q) {
            const int lrow = g * 4 + q;
            scb[lrow * PS + 256 + o]  = f2bf(sqrtf(sv[q]));
            dotb[lrow * PD + 128 + o] = f2bf(suv[q] * 0.5773502691896258f);
        }
    } else if (wave < 6) {          // l2: tile tt = wave-4, 5 channels, K=32
        const int tt = wave - 4, o = tt * 16 + r;
        float sv[4] = {0.f,0.f,0.f,0.f}, suv[4] = {0.f,0.f,0.f,0.f};
        #pragma unroll
        for (int ch = 0; ch < 5; ++ch) {
            f32x4 au = mm_acc<1, PACKED>(fin + 320 + 32 * ch, PF,
                PACKED ? (const void*)(P.ws + B_UW2) : (const void*)P.Uw2, 32, tt, lane);
            f32x4 av = mm_acc<1, PACKED>(fin + 320 + 32 * ch, PF,
                PACKED ? (const void*)(P.ws + B_VW2) : (const void*)P.Vw2, 32, tt, lane);
            #pragma unroll
            for (int q = 0; q < 4; ++q) {
                const float U = au[q] * 0.17677669529663687f, V = av[q] * 0.17677669529663687f;
                uxr[ch][q] = U; sv[q] += V * V; suv[q] += U * V;
            }
        }
        #pragma unroll
        for (int q = 0; q < 4; ++q) {
            const int lrow = g * 4 + q;
            scb[lrow * PS + 320 + o]  = f2bf(sqrtf(sv[q]));
            dotb[lrow * PD + 192 + o] = f2bf(suv[q] * 0.4472135954999579f);
        }
    }
    __syncthreads();

    // ---------------- S4: mlp1 + silu -> hb ----------------
    {
        f32x4 acc = mm_acc<11, PACKED>(scb, PS,
            PACKED ? (const void*)(P.ws + B_W1) : (const void*)P.w1, 128, wave, lane);
        const int o = wave * 16 + r;
        const float bv = bf2f(bcom[256 + o]);
        #pragma unroll
        for (int q = 0; q < 4; ++q) {
            float x = acc[q] + bv;
            hb[(g * 4 + q) * PH + o] = f2bf(x / (1.f + expf(-x)));
        }
    }
    __syncthreads();

    // ---------------- S5: mlp2 + inner with fused spherical residual ----------------
    // Tile->wave map: tiles `wave` and `wave+8` produce exactly the a_vv columns whose
    // U values this wave holds -> no LDS for a_vv, no cross-barrier register persistence.
    {
        float avv0[4], avv1[4];
        {   // ti = wave: a_vv cols 16w.. (matches u0r)
            f32x4 acc = mm_acc<4, PACKED>(hb, PH,
                PACKED ? (const void*)(P.ws + B_W2) : (const void*)P.w2, 480, wave, lane);
            const float bv = bf2f(bcom[384 + wave * 16 + r]);
            #pragma unroll
            for (int q = 0; q < 4; ++q) avv0[q] = acc[q] + bv;
        }
        {   // ti = wave+8: waves 0-5 a_vv l1/l2 cols (matches uxr); waves 6,7 a_sv start
            const int ti = wave + 8;
            f32x4 acc = mm_acc<4, PACKED>(hb, PH,
                PACKED ? (const void*)(P.ws + B_W2) : (const void*)P.w2, 480, ti, lane);
            const int o = ti * 16 + r;
            const float bv = bf2f(bcom[384 + o]);
            if (wave < 6) {
                #pragma unroll
                for (int q = 0; q < 4; ++q) avv1[q] = acc[q] + bv;
            } else {
                #pragma unroll
                for (int q = 0; q < 4; ++q)
                    aout2[(g * 4 + q) * PA2 + (o - 224)] = f2bf(acc[q] + bv);
            }
        }
        // spherical residual: out = xp + U * a_vv (registers only; scalar stores)
        {
            const size_t ob = (size_t)NROWS * 128;
            const int o = wave * 16 + r;
            #pragma unroll
            for (int q = 0; q < 4; ++q) {
                const size_t gr = (size_t)(row0 + g * 4 + q) * 480;
                P.out[ob + gr + o] = P.xp[gr + o] + u0r[q] * avv0[q];
            }
            if (wave < 4) {
                const int i = wave * 16 + r;
                #pragma unroll
                for (int q = 0; q < 4; ++q) {
                    const size_t gr = (size_t)(row0 + g * 4 + q) * 480;
                    #pragma unroll
                    for (int ch = 0; ch < 3; ++ch) {
                        const size_t c = 128 + 3 * i + ch;
                        P.out[ob + gr + c] = P.xp[gr + c] + uxr[ch][q] * avv1[q];
                    }
                }
            } else if (wave < 6) {
                const int i = (wave - 4) * 16 + r;
                #pragma unroll
                for (int q = 0; q < 4; ++q) {
                    const size_t gr = (size_t)(row0 + g * 4 + q) * 480;
                    #pragma unroll
                    for (int ch = 0; ch < 5; ++ch) {
                        const size_t c = 320 + 5 * i + ch;
                        P.out[ob + gr + c] = P.xp[gr + c] + uxr[ch][q] * avv1[q];
                    }
                }
            }
        }
        // remaining tiles: mlp2 a_sv/a_ss (16..29) and inner (30..37)
        for (int ti = wave + 16; ti < 38; ti += 8) {
            if (ti < 30) {
                f32x4 acc = mm_acc<4, PACKED>(hb, PH,
                    PACKED ? (const void*)(P.ws + B_W2) : (const void*)P.w2, 480, ti, lane);
                const int o = ti * 16 + r;
                const float bv = bf2f(bcom[384 + o]);
                #pragma unroll
                for (int q = 0; q < 4; ++q)
                    aout2[(g * 4 + q) * PA2 + (o - 224)] = f2bf(acc[q] + bv);
            } else {
                f32x4 acc = mm_acc<7, PACKED>(dotb, PD,
                    PACKED ? (const void*)(P.ws + B_DW) : (const void*)P.dw, 128, ti - 30, lane);
                const int oo = (ti - 30) * 16 + r;
                #pragma unroll
                for (int q = 0; q < 4; ++q)
                    innerF[(g * 4 + q) * PIF + oo] = acc[q];
            }
        }
    }
    __syncthreads();

    // ---------------- S6: scalar residual: out = xs + a_sv*inner + a_ss ----------------
    {
        const int r2 = tid >> 5, c4 = (tid & 31) * 4;
        const size_t gb = (size_t)(row0 + r2) * 128 + c4;
        const u16x4 asv = *(const u16x4*)(aout2 + r2 * PA2 + c4);
        const u16x4 ass = *(const u16x4*)(aout2 + r2 * PA2 + 128 + c4);
        const f32x4 inn = *(const f32x4*)(innerF + r2 * PIF + c4);
        const f32x4 xs = *(const f32x4*)(P.xs + gb);
        f32x4 o;
        #pragma unroll
        for (int j = 0; j < 4; ++j)
            o[j] = xs[j] + bf2f(asv[j]) * inn[j] + bf2f(ass[j]);
        *(f32x4*)(P.out + gb) = o;
    }
}

extern "C" void kernel_launch(void* const* d_in, const int* in_sizes, int n_in,
                              void* d_out, int out_size, void* d_ws, size_t ws_size,
                              hipStream_t stream)
{
    Ptrs P;
    P.xs  = (const float*)d_in[0];  P.xp  = (const float*)d_in[1];
    P.lng = (const float*)d_in[2];  P.lnb = (const float*)d_in[3];
    P.o3w = (const float*)d_in[4];  P.o3b = (const float*)d_in[5];
    P.Uw0 = (const float*)d_in[6];  P.Uw1 = (const float*)d_in[7];
    P.Uw2 = (const float*)d_in[8];  P.Ub0 = (const float*)d_in[9];
    P.Vw0 = (const float*)d_in[10]; P.Vw1 = (const float*)d_in[11];
    P.Vw2 = (const float*)d_in[12]; P.Vb0 = (const float*)d_in[13];
    P.dw  = (const float*)d_in[14]; P.w1  = (const float*)d_in[15];
    P.b1  = (const float*)d_in[16]; P.w2  = (const float*)d_in[17];
    P.b2  = (const float*)d_in[18];
    P.ws  = (const u16*)d_ws;
    P.out = (float*)d_out;

    const bool packed = (ws_size >= (size_t)PACK_TOT * sizeof(u16));
    if (packed) {
        pack_weights<<<(PACK_TOT + 255) / 256, 256, 0, stream>>>(P, (u16*)d_ws);
        xpainn_main<true><<<NBLK, NTHR, 0, stream>>>(P);
    } else {
        xpainn_main<false><<<NBLK, NTHR, 0, stream>>>(P);
    }
}